// Round 2
// baseline (77.215 us; speedup 1.0000x reference)
//
#include <hip/hip_runtime.h>
#include <math.h>

// PolicyNetwork3x3, batch 1, ~3k MACs. Single wave (64 lanes).
// All weight loads are issued up-front into registers (independent of the
// activation dataflow), so the critical path is just 5 LDS round-trips:
//   x -> conv -> fc -> {a1 | v1} -> {a2 logits | v2 tanh} -> masked softmax.
// fc (32 rows x 64) is split across lane pairs (t, t^32), combined with
// __shfl_xor; heads are role-assigned: lanes 0..15 a1, 16..23 v1,
// 24..32 a2, 34 v2.

__global__ __launch_bounds__(64) void policy3x3_kernel(
    const float* __restrict__ x,      // 9
    const float* __restrict__ conv_w, // 64   (16 rows x 4)
    const float* __restrict__ fc_w,   // 2048 (32 rows x 64)
    const float* __restrict__ fc_b,   // 32
    const float* __restrict__ a1_w,   // 512  (16 rows x 32)
    const float* __restrict__ a1_b,   // 16
    const float* __restrict__ a2_w,   // 144  (9 rows x 16)
    const float* __restrict__ a2_b,   // 9
    const float* __restrict__ v1_w,   // 256  (8 rows x 32)
    const float* __restrict__ v1_b,   // 8
    const float* __restrict__ v2_w,   // 8
    const float* __restrict__ v2_b,   // 1
    float* __restrict__ out)          // 10: prob[9], value[1]
{
    __shared__ float s_x[9];
    __shared__ float s_f[64];
    __shared__ float s_y[32];
    __shared__ float s_ah[16];
    __shared__ float s_vh[8];
    __shared__ float s_logit[9];

    const int t = threadIdx.x;

    // ---------- Phase A: issue ALL global loads up-front ----------
    // conv weights: one float4 row per 4 lanes (broadcast within quad)
    const float4 cw = ((const float4*)conv_w)[t >> 2];

    // fc: lane pair (r = t&31, h = t>>5) each takes half a 64-wide row
    const int r = t & 31;
    const int h = t >> 5;
    float4 fw[8];
    {
        const float4* p = (const float4*)fc_w + r * 16 + h * 8;
#pragma unroll
        for (int i = 0; i < 8; ++i) fw[i] = p[i];
    }
    const float fb = fc_b[r];

    // head weights by lane role
    float4 hw[8];
    float  hb = 0.f;
    if (t < 16) {                    // a1 row t (32 w)
        const float4* p = (const float4*)a1_w + t * 8;
#pragma unroll
        for (int i = 0; i < 8; ++i) hw[i] = p[i];
        hb = a1_b[t];
    } else if (t < 24) {             // v1 row t-16 (32 w)
        const float4* p = (const float4*)v1_w + (t - 16) * 8;
#pragma unroll
        for (int i = 0; i < 8; ++i) hw[i] = p[i];
        hb = v1_b[t - 16];
    } else if (t < 33) {             // a2 row t-24 (16 w)
        const float4* p = (const float4*)a2_w + (t - 24) * 4;
#pragma unroll
        for (int i = 0; i < 4; ++i) hw[i] = p[i];
        hb = a2_b[t - 24];
    } else if (t == 34) {            // v2 (8 w)
        hw[0] = ((const float4*)v2_w)[0];
        hw[1] = ((const float4*)v2_w)[1];
        hb = v2_b[0];
    }

    // board
    if (t < 9) s_x[t] = x[t];
    __syncthreads();

    // ---------- conv + relu: flat[oc*4 + oh*2 + ow], one elem/lane ----------
    {
        const int pos = t & 3;
        const int oh  = pos >> 1;
        const int ow  = pos & 1;
        float f = cw.x * s_x[oh * 3 + ow]
                + cw.y * s_x[oh * 3 + ow + 1]
                + cw.z * s_x[(oh + 1) * 3 + ow]
                + cw.w * s_x[(oh + 1) * 3 + ow + 1];
        s_f[t] = fmaxf(f, 0.f);
    }
    __syncthreads();

    // ---------- fc: pair-split dot, combine across t^32 ----------
    {
        float acc = 0.f;
        const float* sf = s_f + h * 32;
#pragma unroll
        for (int i = 0; i < 8; ++i)
            acc += fw[i].x * sf[i * 4 + 0] + fw[i].y * sf[i * 4 + 1]
                 + fw[i].z * sf[i * 4 + 2] + fw[i].w * sf[i * 4 + 3];
        acc += __shfl_xor(acc, 32);
        // both lanes of the pair write the identical value — benign
        s_y[r] = fmaxf(acc + fb, 0.f);
    }
    __syncthreads();

    // ---------- a1 (lanes 0..15) and v1 (lanes 16..23) ----------
    if (t < 16) {
        float a = hb;
#pragma unroll
        for (int i = 0; i < 8; ++i)
            a += hw[i].x * s_y[i * 4 + 0] + hw[i].y * s_y[i * 4 + 1]
               + hw[i].z * s_y[i * 4 + 2] + hw[i].w * s_y[i * 4 + 3];
        s_ah[t] = fmaxf(a, 0.f);
    } else if (t < 24) {
        float a = hb;
#pragma unroll
        for (int i = 0; i < 8; ++i)
            a += hw[i].x * s_y[i * 4 + 0] + hw[i].y * s_y[i * 4 + 1]
               + hw[i].z * s_y[i * 4 + 2] + hw[i].w * s_y[i * 4 + 3];
        s_vh[t - 16] = fmaxf(a, 0.f);
    }
    __syncthreads();

    // ---------- a2 logits (lanes 24..32) and value head (lane 34) ----------
    if (t >= 24 && t < 33) {
        float a = hb;
#pragma unroll
        for (int i = 0; i < 4; ++i)
            a += hw[i].x * s_ah[i * 4 + 0] + hw[i].y * s_ah[i * 4 + 1]
               + hw[i].z * s_ah[i * 4 + 2] + hw[i].w * s_ah[i * 4 + 3];
        s_logit[t - 24] = a;
    } else if (t == 34) {
        float a = hb;
        a += hw[0].x * s_vh[0] + hw[0].y * s_vh[1]
           + hw[0].z * s_vh[2] + hw[0].w * s_vh[3];
        a += hw[1].x * s_vh[4] + hw[1].y * s_vh[5]
           + hw[1].z * s_vh[6] + hw[1].w * s_vh[7];
        out[9] = tanhf(a);
    }
    __syncthreads();

    // ---------- masked softmax (lane 0) ----------
    if (t == 0) {
        float maxa = s_logit[0];
#pragma unroll
        for (int c = 1; c < 9; ++c) maxa = fmaxf(maxa, s_logit[c]);
        float e[9];
        float sum = 0.f;
#pragma unroll
        for (int c = 0; c < 9; ++c) {
            const float avail = (fabsf(s_x[c]) != 1.0f) ? 1.0f : 0.0f;
            e[c] = avail * __expf(s_logit[c] - maxa);
            sum += e[c];
        }
        const float inv = 1.0f / sum;
#pragma unroll
        for (int c = 0; c < 9; ++c) out[c] = e[c] * inv;
    }
}

extern "C" void kernel_launch(void* const* d_in, const int* in_sizes, int n_in,
                              void* d_out, int out_size, void* d_ws, size_t ws_size,
                              hipStream_t stream) {
    (void)in_sizes; (void)n_in; (void)d_ws; (void)ws_size; (void)out_size;
    const float* x      = (const float*)d_in[0];
    const float* conv_w = (const float*)d_in[1];
    const float* fc_w   = (const float*)d_in[2];
    const float* fc_b   = (const float*)d_in[3];
    const float* a1_w   = (const float*)d_in[4];
    const float* a1_b   = (const float*)d_in[5];
    const float* a2_w   = (const float*)d_in[6];
    const float* a2_b   = (const float*)d_in[7];
    const float* v1_w   = (const float*)d_in[8];
    const float* v1_b   = (const float*)d_in[9];
    const float* v2_w   = (const float*)d_in[10];
    const float* v2_b   = (const float*)d_in[11];
    float* out = (float*)d_out;

    hipLaunchKernelGGL(policy3x3_kernel, dim3(1), dim3(64), 0, stream,
                       x, conv_w, fc_w, fc_b, a1_w, a1_b, a2_w, a2_b,
                       v1_w, v1_b, v2_w, v2_b, out);
}